// Round 4
// baseline (371.740 us; speedup 1.0000x reference)
//
#include <hip/hip_runtime.h>
#include <math.h>

#define QMAX 127.0f
#define CIN 32
#define CR 8
#define HW 16384                 // 128*128
#define BATCH 64
#define NPIX (BATCH*HW)          // 1,048,576 pixels
#define NPAIR (NPIX/2)           // 524,288 pixel-pairs
#define NQUAD (NPIX/4)           // 262,144 pixel-quads
#define NX (BATCH*CIN*HW)        // 33,554,432 x elements

// ws layout: wsu[0]=amax_x bits, wsu[1]=amax_h bits, wsu[2..3] spare;
// h buffer at wsf+64 when workspace is big enough
#define H_OFF 64
#define WS_NEEDED ((size_t)(H_OFF + (size_t)NPIX * CR) * 4)

typedef float v2f __attribute__((ext_vector_type(2)));

__device__ __forceinline__ float fq(float v, float inv_scale, float scale) {
    return rintf(fminf(fmaxf(v * inv_scale, -QMAX), QMAX)) * scale;  // round-half-even
}
__device__ __forceinline__ float sigmoidf_(float v) {
    return __builtin_amdgcn_rcpf(1.0f + __expf(-v));   // v_rcp_f32: ~1ulp, fine vs 5.5e-2 thr
}
__device__ __forceinline__ v2f nt_load2(const float* p) {
    return __builtin_nontemporal_load((const v2f*)p);
}
__device__ __forceinline__ void nt_store2(float* p, float a, float b) {
    v2f v; v.x = a; v.y = b;
    __builtin_nontemporal_store(v, (v2f*)p);
}

// ---------------- k1: global max|x| ----------------
// 4096 blocks x 256 thr x 8 float4 = NX. Tiny VGPR -> ~32 waves/CU.
__global__ __launch_bounds__(256) void k1_xmax(const float4* __restrict__ x4,
                                               unsigned int* __restrict__ wsu) {
    int idx = blockIdx.x * 256 + threadIdx.x;      // [0, 1,048,576)
    float4 v[8];
#pragma unroll
    for (int i = 0; i < 8; i++) v[i] = x4[idx + i * 1048576];
    __builtin_amdgcn_sched_barrier(0);
    float m = 0.f;
#pragma unroll
    for (int i = 0; i < 8; i++)
        m = fmaxf(m, fmaxf(fmaxf(fabsf(v[i].x), fabsf(v[i].y)),
                           fmaxf(fabsf(v[i].z), fabsf(v[i].w))));
#pragma unroll
    for (int off = 32; off > 0; off >>= 1) m = fmaxf(m, __shfl_xor(m, off, 64));
    __shared__ float red[4];
    int t = threadIdx.x;
    if ((t & 63) == 0) red[t >> 6] = m;
    __syncthreads();
    if (t == 0) {
        m = fmaxf(fmaxf(red[0], red[1]), fmaxf(red[2], red[3]));
        atomicMax(&wsu[0], __float_as_uint(m));   // values >=0: uint order == float order
    }
}

// ---------------- k2: h = SiLU(conv_reduce(quant(x))); global max|h|; store h ----------------
// 2048 blocks x 256 thr, one float2 (2 pixels) per thread. 16-deep load staging.
__global__ __launch_bounds__(256) void k2_hmax(const float* __restrict__ x,
                                               const float* __restrict__ wr,
                                               const float* __restrict__ br,
                                               const unsigned int* __restrict__ wsu,
                                               unsigned int* __restrict__ hmax,
                                               float* __restrict__ hbuf) {
    __shared__ float wq[CR * CIN], bsh[CR], amr[CR];
    int t = threadIdx.x;
    if (t < CR) {
        float mm = 0.f;
        for (int c = 0; c < CIN; c++) mm = fmaxf(mm, fabsf(wr[t * CIN + c]));
        amr[t] = fmaxf(mm, 1e-12f);
        bsh[t] = br[t];
    }
    __syncthreads();
    {
        float amax = amr[t >> 5];
        wq[t] = fq(wr[t], QMAX / amax, amax * (1.f / QMAX));
    }
    __syncthreads();
    float a_amax = fmaxf(__uint_as_float(wsu[0]), 1e-12f);
    float ascale = a_amax * (1.f / QMAX), ainv = QMAX / a_amax;

    int tid = blockIdx.x * 256 + t;            // [0, NPAIR)
    int b = tid >> 13;                         // 8192 pairs per image
    int hw = (tid & 8191) << 1;
    const float* xb = x + (size_t)b * CIN * HW + hw;

    float hacc[CR][2];
#pragma unroll
    for (int o = 0; o < CR; o++) { hacc[o][0] = 0.f; hacc[o][1] = 0.f; }

#pragma unroll
    for (int s = 0; s < 2; s++) {              // two stages of 16 channels
        float2 xv[16];
#pragma unroll
        for (int j = 0; j < 16; j++)
            xv[j] = *(const float2*)(xb + (size_t)(s * 16 + j) * HW);
        __builtin_amdgcn_sched_barrier(0);     // keep the 16 loads issued as a batch
#pragma unroll
        for (int j4 = 0; j4 < 4; j4++) {       // consume 4 channels at a time
            float q0[4], q1[4];
#pragma unroll
            for (int k = 0; k < 4; k++) {
                q0[k] = fq(xv[j4 * 4 + k].x, ainv, ascale);
                q1[k] = fq(xv[j4 * 4 + k].y, ainv, ascale);
            }
            int c0 = s * 16 + j4 * 4;
#pragma unroll
            for (int o = 0; o < CR; o++) {
                float4 wv = *(const float4*)&wq[o * CIN + c0];  // ds_read_b128, broadcast
                hacc[o][0] += q0[0]*wv.x + q0[1]*wv.y + q0[2]*wv.z + q0[3]*wv.w;
                hacc[o][1] += q1[0]*wv.x + q1[1]*wv.y + q1[2]*wv.z + q1[3]*wv.w;
            }
        }
    }

    float m = 0.f;
#pragma unroll
    for (int o = 0; o < CR; o++) {
        float bb = bsh[o];
        float h0 = hacc[o][0] + bb; h0 = h0 * sigmoidf_(h0);
        float h1 = hacc[o][1] + bb; h1 = h1 * sigmoidf_(h1);
        m = fmaxf(m, fmaxf(fabsf(h0), fabsf(h1)));
        if (hbuf) {
            float2 hv; hv.x = h0; hv.y = h1;
            *(float2*)(hbuf + (size_t)(b * CR + o) * HW + hw) = hv;  // cached: k3 rereads
        }
    }
#pragma unroll
    for (int off = 32; off > 0; off >>= 1) m = fmaxf(m, __shfl_xor(m, off, 64));
    __shared__ float red[4];
    if ((t & 63) == 0) red[t >> 6] = m;
    __syncthreads();
    if (t == 0) {
        m = fmaxf(fmaxf(red[0], red[1]), fmaxf(red[2], red[3]));
        atomicMax(hmax, __float_as_uint(m));
    }
}

// ---------------- k3: g = conv_expand(quant(h)); out = identity * sigmoid(g) ----------------
// 2048 blocks x 256 thr, one float2 per thread. NT loads on identity, NT stores on out.
__global__ __launch_bounds__(256) void k3_out(const float* __restrict__ hbuf,
                                              const float* __restrict__ identity,
                                              const float* __restrict__ we,
                                              const float* __restrict__ be,
                                              const unsigned int* __restrict__ wsu,
                                              float* __restrict__ out) {
    __shared__ float wqe[CIN * CR], besh[CIN], ame[CIN];
    int t = threadIdx.x;
    if (t < CIN) {
        float mm = 0.f;
        for (int c = 0; c < CR; c++) mm = fmaxf(mm, fabsf(we[t * CR + c]));
        ame[t] = fmaxf(mm, 1e-12f);
        besh[t] = be[t];
    }
    __syncthreads();
    {
        float amax = ame[t >> 3];
        wqe[t] = fq(we[t], QMAX / amax, amax * (1.f / QMAX));
    }
    __syncthreads();
    float h_amax = fmaxf(__uint_as_float(wsu[1]), 1e-12f);
    float hscale = h_amax * (1.f / QMAX), hinv = QMAX / h_amax;

    int tid = blockIdx.x * 256 + t;
    int b = tid >> 13;
    int hw = (tid & 8191) << 1;

    float2 hv[CR];
#pragma unroll
    for (int cr = 0; cr < CR; cr++)
        hv[cr] = *(const float2*)(hbuf + (size_t)(b * CR + cr) * HW + hw);
    __builtin_amdgcn_sched_barrier(0);
    float hq0[CR], hq1[CR];
#pragma unroll
    for (int cr = 0; cr < CR; cr++) {
        hq0[cr] = fq(hv[cr].x, hinv, hscale);
        hq1[cr] = fq(hv[cr].y, hinv, hscale);
    }

    const size_t base = (size_t)b * CIN * HW + hw;
#pragma unroll
    for (int og = 0; og < 4; og++) {           // 4 groups of 8 output channels
        v2f idv[8];
#pragma unroll
        for (int j = 0; j < 8; j++)
            idv[j] = nt_load2(identity + base + (size_t)(og * 8 + j) * HW);
        __builtin_amdgcn_sched_barrier(0);
#pragma unroll
        for (int j = 0; j < 8; j++) {
            int o2 = og * 8 + j;
            float4 w0 = *(const float4*)&wqe[o2 * CR];
            float4 w1 = *(const float4*)&wqe[o2 * CR + 4];
            float g0 = besh[o2]
                + hq0[0]*w0.x + hq0[1]*w0.y + hq0[2]*w0.z + hq0[3]*w0.w
                + hq0[4]*w1.x + hq0[5]*w1.y + hq0[6]*w1.z + hq0[7]*w1.w;
            float g1 = besh[o2]
                + hq1[0]*w0.x + hq1[1]*w0.y + hq1[2]*w0.z + hq1[3]*w0.w
                + hq1[4]*w1.x + hq1[5]*w1.y + hq1[6]*w1.z + hq1[7]*w1.w;
            nt_store2(out + base + (size_t)o2 * HW,
                      idv[j].x * sigmoidf_(g0), idv[j].y * sigmoidf_(g1));
        }
    }
}

// ---------------- small-ws fallback: recompute h in k3 (proven kernel) ----------------
__global__ __launch_bounds__(256) void k3_out_rc(const float* __restrict__ x,
                                                 const float* __restrict__ identity,
                                                 const float* __restrict__ wr,
                                                 const float* __restrict__ br,
                                                 const float* __restrict__ we,
                                                 const float* __restrict__ be,
                                                 const unsigned int* __restrict__ wsu,
                                                 float* __restrict__ out) {
    __shared__ float wqr[CR * CIN], wqe[CIN * CR], bsh[CR], besh[CIN], amr[CR], ame[CIN];
    int t = threadIdx.x;
    if (t < CR) {
        float mm = 0.f;
        for (int c = 0; c < CIN; c++) mm = fmaxf(mm, fabsf(wr[t * CIN + c]));
        amr[t] = fmaxf(mm, 1e-12f);
        bsh[t] = br[t];
    }
    if (t >= 64 && t < 64 + CIN) {
        int r = t - 64;
        float mm = 0.f;
        for (int c = 0; c < CR; c++) mm = fmaxf(mm, fabsf(we[r * CR + c]));
        ame[r] = fmaxf(mm, 1e-12f);
        besh[r] = be[r];
    }
    __syncthreads();
    {
        float amax = amr[t >> 5];
        wqr[t] = fq(wr[t], QMAX / amax, amax * (1.f / QMAX));
        float amax2 = ame[t >> 3];
        wqe[t] = fq(we[t], QMAX / amax2, amax2 * (1.f / QMAX));
    }
    __syncthreads();
    float a_amax = fmaxf(__uint_as_float(wsu[0]), 1e-12f);
    float ascale = a_amax * (1.f / QMAX), ainv = QMAX / a_amax;
    float h_amax = fmaxf(__uint_as_float(wsu[1]), 1e-12f);
    float hscale = h_amax * (1.f / QMAX), hinv = QMAX / h_amax;
    int tid = blockIdx.x * 256 + t;
    int b = tid >> 12;
    int hw = (tid & 4095) << 2;
    size_t base = (size_t)b * CIN * HW + hw;
    const float* xb = x + base;
    float hq[CR][4];
    {
        float hacc[CR][4];
#pragma unroll
        for (int o = 0; o < CR; o++)
#pragma unroll
            for (int v = 0; v < 4; v++) hacc[o][v] = 0.f;
#pragma unroll
        for (int c = 0; c < CIN; c++) {
            float4 xv = *(const float4*)(xb + (size_t)c * HW);
            float q0 = fq(xv.x, ainv, ascale), q1 = fq(xv.y, ainv, ascale);
            float q2 = fq(xv.z, ainv, ascale), q3 = fq(xv.w, ainv, ascale);
#pragma unroll
            for (int o = 0; o < CR; o++) {
                float w = wqr[o * CIN + c];
                hacc[o][0] += q0 * w; hacc[o][1] += q1 * w;
                hacc[o][2] += q2 * w; hacc[o][3] += q3 * w;
            }
        }
#pragma unroll
        for (int o = 0; o < CR; o++) {
            float bb = bsh[o];
#pragma unroll
            for (int v = 0; v < 4; v++) {
                float h = hacc[o][v] + bb;
                h = h * sigmoidf_(h);
                hq[o][v] = fq(h, hinv, hscale);
            }
        }
    }
#pragma unroll 4
    for (int o2 = 0; o2 < CIN; o2++) {
        float g0 = besh[o2], g1 = g0, g2 = g0, g3 = g0;
#pragma unroll
        for (int cr = 0; cr < CR; cr++) {
            float w = wqe[o2 * CR + cr];
            g0 += hq[cr][0] * w; g1 += hq[cr][1] * w;
            g2 += hq[cr][2] * w; g3 += hq[cr][3] * w;
        }
        size_t off = base + (size_t)o2 * HW;
        float4 idv = *(const float4*)(identity + off);
        float4 ov;
        ov.x = idv.x * sigmoidf_(g0);
        ov.y = idv.y * sigmoidf_(g1);
        ov.z = idv.z * sigmoidf_(g2);
        ov.w = idv.w * sigmoidf_(g3);
        *(float4*)(out + off) = ov;
    }
}

extern "C" void kernel_launch(void* const* d_in, const int* in_sizes, int n_in,
                              void* d_out, int out_size, void* d_ws, size_t ws_size,
                              hipStream_t stream) {
    const float* x        = (const float*)d_in[0];
    const float* identity = (const float*)d_in[1];
    const float* wr       = (const float*)d_in[2];
    const float* br       = (const float*)d_in[3];
    const float* we       = (const float*)d_in[4];
    const float* be       = (const float*)d_in[5];
    float* out            = (float*)d_out;
    float* wsf            = (float*)d_ws;
    unsigned int* wsu     = (unsigned int*)d_ws;

    hipMemsetAsync(d_ws, 0, 16, stream);   // zero the two amax accumulators

    const bool big_ws = (ws_size >= WS_NEEDED);
    float* hbuf = big_ws ? (wsf + H_OFF) : nullptr;

    hipLaunchKernelGGL(k1_xmax, dim3(4096), dim3(256), 0, stream, (const float4*)x, wsu);
    hipLaunchKernelGGL(k2_hmax, dim3(NPAIR / 256), dim3(256), 0, stream,
                       x, wr, br, wsu, &wsu[1], hbuf);
    if (big_ws) {
        hipLaunchKernelGGL(k3_out, dim3(NPAIR / 256), dim3(256), 0, stream,
                           hbuf, identity, we, be, wsu, out);
    } else {
        hipLaunchKernelGGL(k3_out_rc, dim3(NQUAD / 256), dim3(256), 0, stream,
                           x, identity, wr, br, we, be, wsu, out);
    }
}